// Round 5
// baseline (108.776 us; speedup 1.0000x reference)
//
#include <hip/hip_runtime.h>
#include <math.h>

// ---------------------------------------------------------------------------
// FullGaussianProjector: B=1, N=512, 3 views, 224x224 out, half-res 112x112.
// R10: break hot-tile serialization. 2 dispatches:
//   kernel 1 (splat, 512 thr, grid 14x14x12): each tile's gaussian list is
//     split K=4 ways across INDEPENDENT blocks (z = view*4 + chunk). R9
//     post-mortem: one hot tile (len~512) = ~8us on one block; CUs drawing
//     2-3 hot blocks set a ~20-30us wall. Sub-blocks cull/compact the full
//     list identically (deterministic LDS-scan compaction, NOT atomicAdd —
//     all sub-blocks must agree on list order), evaluate only their quarter,
//     and write per-pixel partials (S, mn, mx) to part[v][y][x][field*4+k].
//     No atomics, no init: every slot is written unconditionally (len==0
//     naturally yields S=0, mn=0, mx=0 via the len<512 zero-clamp).
//   kernel 2 (blur_norm, 256 thr): merges the 4 partials per halo pixel
//     (3x float4 loads) and applies the closed-form dmv at load time, then
//     blur2 + stats + cheap LLC grid barrier (R9-proven: spread arrival,
//     single poller, read-only release spin) + normalize from registers.
// Closed forms:
//   dmv = 0.5*(S - 512*mn)/(mx - mn + eps) + S/(S + eps)
//   bilinear(quadratic) = quad(Ex,Ey) - (a*Vx + c*Vy)
// NOTE (R5 lesson): a,2b,c,op must stay f32 — bf16 on the exponent path
// fails absmax through the (wmax-wmin) normalization.
// ---------------------------------------------------------------------------

#define NBLOCKS 588u
#define NARR 32                // arrival counters, one per 128B cacheline
#define FLAG_IDX (NARR * 32)   // release flag, its own cacheline
#define KSPLIT 4

__device__ __forceinline__ float g_ld(const float* p) {
    return __hip_atomic_load(p, __ATOMIC_RELAXED, __HIP_MEMORY_SCOPE_AGENT);
}
__device__ __forceinline__ void g_st(float* p, float v) {
    __hip_atomic_store(p, v, __ATOMIC_RELAXED, __HIP_MEMORY_SCOPE_AGENT);
}

// Cheap grid barrier: spread arrival + single poller + broadcast release.
// No cache maintenance; cross-block data must use agent-scope atomics.
__device__ __forceinline__ void grid_barrier(unsigned* cnts, int arrIdx, bool poller) {
    __syncthreads();
    if (threadIdx.x == 0) {
        asm volatile("s_waitcnt vmcnt(0)" ::: "memory");  // partials acked at LLC
        __hip_atomic_fetch_add(&cnts[arrIdx * 32], 1u,
                               __ATOMIC_RELAXED, __HIP_MEMORY_SCOPE_AGENT);
        unsigned* flagp = &cnts[FLAG_IDX];
        if (poller) {
            for (;;) {
                unsigned s = 0;
                #pragma unroll
                for (int i = 0; i < NARR; ++i)
                    s += __hip_atomic_load(&cnts[i * 32],
                                           __ATOMIC_RELAXED, __HIP_MEMORY_SCOPE_AGENT);
                if (s == NBLOCKS) break;
                __builtin_amdgcn_s_sleep(2);
            }
            asm volatile("" ::: "memory");  // flag store after poll loads
            __hip_atomic_store(flagp, 1u, __ATOMIC_RELAXED, __HIP_MEMORY_SCOPE_AGENT);
        } else {
            while (__hip_atomic_load(flagp, __ATOMIC_RELAXED,
                                     __HIP_MEMORY_SCOPE_AGENT) == 0u)
                __builtin_amdgcn_s_sleep(2);
        }
    }
    __syncthreads();
}

__device__ __forceinline__ float wave_min(float v) {
    #pragma unroll
    for (int o = 32; o >= 1; o >>= 1) v = fminf(v, __shfl_xor(v, o));
    return v;
}

// Block: 512 threads (8 waves), tile 16x16 full-res px (8x8 quads).
// Grid (14, 14, 3*KSPLIT): z = v*KSPLIT + kk; this block evaluates chunk kk
// of the tile's compacted list and writes per-pixel partials.
__global__ __launch_bounds__(512) void splat_part_kernel(
    const float* __restrict__ position, const float* __restrict__ cov3d,
    const float* __restrict__ opacity, const float* __restrict__ importance,
    float* __restrict__ part, unsigned* __restrict__ cnts) {
    __shared__ float4 lsA[512];        // a, 2b, c, op
    __shared__ float2 lsB[512];        // gx, gy
    __shared__ float red[8 * 6];       // cross-wave min/max scratch
    __shared__ int wcnt[8];            // per-wave cull counts (deterministic scan)
    __shared__ float4 pS[7][64], pMn[7][64], pMx[7][64];
    const int v  = blockIdx.z >> 2;
    const int kk = blockIdx.z & 3;
    const int tx0 = blockIdx.x * 16, ty0 = blockIdx.y * 16;
    const int tid = threadIdx.x;
    const int lane = tid & 63, wave = tid >> 6;

    // clear kernel-2 barrier counters + flag (ws is poisoned each iteration;
    // the kernel boundary flush makes this visible before kernel 2 starts)
    if (blockIdx.x == 0 && blockIdx.y == 0 && blockIdx.z == 0) {
        for (int i = tid; i <= FLAG_IDX; i += 512) cnts[i] = 0;
    }

    // ---------------- setup (1 gaussian per thread) ----------------
    const int n = tid;
    const float p0 = position[n * 3 + 0];
    const float p1 = position[n * 3 + 1];
    const float p2 = position[n * 3 + 2];
    const float opimp = opacity[n] * fminf(fmaxf(importance[n], 0.5f), 2.0f);

    {
        float vals[6] = {p0, -p0, p1, -p1, p2, -p2};
        #pragma unroll
        for (int q = 0; q < 6; ++q) {
            float r = wave_min(vals[q]);
            if (lane == 0) red[wave * 6 + q] = r;
        }
    }
    __syncthreads();
    float mn6[6];
    #pragma unroll
    for (int q = 0; q < 6; ++q) {
        float r = red[q];
        #pragma unroll
        for (int w = 1; w < 8; ++w) r = fminf(r, red[w * 6 + q]);
        mn6[q] = r;
    }
    const float pmn[3] = {mn6[0], mn6[2], mn6[4]};
    const float pmx[3] = {-mn6[1], -mn6[3], -mn6[5]};

    float c00 = cov3d[n * 9 + 0], c01 = cov3d[n * 9 + 1], c02 = cov3d[n * 9 + 2];
    float c10 = cov3d[n * 9 + 3], c11 = cov3d[n * 9 + 4], c12 = cov3d[n * 9 + 5];
    float c20 = cov3d[n * 9 + 6], c21 = cov3d[n * 9 + 7], c22 = cov3d[n * 9 + 8];
    for (int vv = 0; vv <= v; ++vv) {
        float s01 = 0.5f * (c01 + c10);
        float s02 = 0.5f * (c02 + c20);
        float s12 = 0.5f * (c12 + c21);
        float s00 = c00 + 1e-6f;
        float s11 = c11 + 1e-6f;
        float s22 = c22 + 1e-6f;
        float nrm = sqrtf(s00 * s00 + s11 * s11 + s22 * s22 +
                          2.0f * (s01 * s01 + s02 * s02 + s12 * s12));
        float inv = 1.0f / (nrm + 1e-6f);
        c00 = s00 * inv; c11 = s11 * inv; c22 = s22 * inv;
        c01 = s01 * inv; c10 = c01; c02 = s02 * inv; c20 = c02;
        c12 = s12 * inv; c21 = c12;
    }
    float cof00 = c11 * c22 - c12 * c12;
    float cof01 = c02 * c12 - c01 * c22;
    float cof02 = c01 * c12 - c02 * c11;
    float det = c00 * cof00 + c01 * cof01 + c02 * cof02;
    float idet = 1.0f / det;
    float i00 = cof00 * idet;
    float i01 = cof01 * idet;
    float i02 = cof02 * idet;
    float i11 = (c00 * c22 - c02 * c02) * idet;
    float i12 = (c02 * c01 - c00 * c12) * idet;
    float i22 = (c00 * c11 - c01 * c01) * idet;

    float Aa, Ab, Ac, prx, pry;
    int ix, iy;
    if (v == 0)      { Aa = i00; Ab = i01; Ac = i11; prx = p0; pry = p1; ix = 0; iy = 1; }
    else if (v == 1) { Aa = i00; Ab = i02; Ac = i22; prx = p0; pry = p2; ix = 0; iy = 2; }
    else             { Aa = i22; Ab = i12; Ac = i11; prx = p2; pry = p1; ix = 2; iy = 1; }
    Aa += 1e-10f;
    Ac += 1e-10f;

    float mnx = pmn[ix], mxx = pmx[ix], mny = pmn[iy], mxy = pmx[iy];
    float rngx = mxx - mnx + 1e-6f;
    float mnx2 = mnx - 0.5f * rngx;
    float mxx2 = mxx + 0.5f * rngx;
    rngx = mxx2 - mnx2 + 1e-6f;
    float rngy = mxy - mny + 1e-6f;
    float mny2 = mny - 0.5f * rngy;
    float mxy2 = mxy + 0.5f * rngy;
    rngy = mxy2 - mny2 + 1e-6f;
    float gx = fminf(fmaxf((prx - mnx2) / rngx * 111.0f, 0.0f), 111.0f);
    float gy = fminf(fmaxf((pry - mny2) / rngy * 111.0f, 0.0f), 111.0f);

    // ------- cull + DETERMINISTIC compact into LDS (SoA f32) -------
    // (scan of per-wave counts, not atomicAdd: every sub-block of this tile
    //  must build the identical list so the K chunks partition it exactly)
    unsigned long long m;
    bool pass;
    {
        const float bx0 = (float)(tx0 >> 1), bx1 = (float)((tx0 + 15) >> 1);
        const float by0 = (float)(ty0 >> 1), by1 = (float)((ty0 + 15) >> 1);
        float dx = fmaxf(fmaxf(bx0 - gx, gx - bx1), 0.0f);
        float dy = fmaxf(fmaxf(by0 - gy, gy - by1), 0.0f);
        pass = (dx * dx + dy * dy) < 400.01f;  // conservative superset
        m = __ballot(pass);
        if (lane == 0) wcnt[wave] = __popcll(m);
    }
    __syncthreads();
    int base = 0, lentot = 0;
    #pragma unroll
    for (int w = 0; w < 8; ++w) {
        int c = wcnt[w];
        if (w < wave) base += c;
        lentot += c;
    }
    if (pass) {
        int slot = base + __popcll(m & ((1ull << lane) - 1ull));
        lsA[slot] = make_float4(Aa, 2.0f * Ab, Ac, opimp);
        lsB[slot] = make_float2(gx, gy);
    }
    __syncthreads();
    const int len = lentot;

    // quad owned by this lane: half-res pixel (xh, yh)
    const int qx = lane & 7, qy = lane >> 3;
    const int xh = (tx0 >> 1) + qx;
    const int yh = (ty0 >> 1) + qy;

    // npad multiple of 64 so each of the 32 (K*waves) chunks is even-sized
    const int npad = (len + 63) & ~63;
    if (tid < npad - len) {  // no-op pad gaussians (mask always fails -> w=0)
        lsA[len + tid] = make_float4(1.0f, 0.0f, 1.0f, 0.0f);
        lsB[len + tid] = make_float2(1e9f, 1e9f);
    }
    __syncthreads();

    // per-parity constants (generic formula, preserves edge clamping exactly)
    float exA[2], eyA[2], VxA[2], VyA[2];
    #pragma unroll
    for (int p = 0; p < 2; ++p) {
        int xlo = xh - 1 + p; int xhi = min(xlo + 1, 111); xlo = max(xlo, 0);
        float wlo = p ? 0.75f : 0.25f, whi = 1.0f - wlo;
        exA[p] = wlo * (float)xlo + whi * (float)xhi;
        VxA[p] = wlo * whi * (float)(xhi - xlo) * (float)(xhi - xlo);
        int ylo = yh - 1 + p; int yhi2 = min(ylo + 1, 111); ylo = max(ylo, 0);
        eyA[p] = wlo * (float)ylo + whi * (float)yhi2;
        VyA[p] = wlo * whi * (float)(yhi2 - ylo) * (float)(yhi2 - ylo);
    }
    const float fxh = (float)xh, fyh = (float)yh;

    // ------- list chunk for this (sub-block, wave): 1/32 of the list -------
    const int chunk = npad >> 5;           // even (npad multiple of 64)
    const int cbeg = ((kk << 3) + wave) * chunk, cend = cbeg + chunk;

    float S00 = 0.f, S01 = 0.f, S10 = 0.f, S11 = 0.f;
    float mn00 = INFINITY, mn01 = INFINITY, mn10 = INFINITY, mn11 = INFINITY;
    float mx00 = -INFINITY, mx01 = -INFINITY, mx10 = -INFINITY, mx11 = -INFINITY;

    for (int i = cbeg; i < cend; i += 2) {
        float4 gA0 = lsA[i], gA1 = lsA[i + 1];
        float2 gB0 = lsB[i], gB1 = lsB[i + 1];
        #pragma unroll
        for (int u = 0; u < 2; ++u) {
            const float4 gA = u ? gA1 : gA0;
            const float2 gB = u ? gB1 : gB0;
            const float a = gA.x, b2 = gA.y, c = gA.z, op = gA.w;
            const float xx = gB.x, yy = gB.y;
            const float dxh = fxh - xx, dyh = fyh - yy;
            const bool inside = dxh * dxh + dyh * dyh < 400.0f;
            const float dx0 = exA[0] - xx, dx1 = exA[1] - xx;
            const float dy0 = eyA[0] - yy, dy1 = eyA[1] - yy;
            const float adx0 = a * dx0, adx1 = a * dx1;
            const float bdy0 = b2 * dy0, bdy1 = b2 * dy1;
            const float cdy0 = c * dy0 * dy0, cdy1 = c * dy1 * dy1;
            const float ax0 = a * VxA[0], ax1 = a * VxA[1];
            const float cy0 = c * VyA[0], cy1 = c * VyA[1];
            #pragma unroll
            for (int py = 0; py < 2; ++py) {
                const float bdyp = py ? bdy1 : bdy0;
                const float cdyp = py ? cdy1 : cdy0;
                const float cyp  = py ? cy1 : cy0;
                #pragma unroll
                for (int px = 0; px < 2; ++px) {
                    const float dxp  = px ? dx1 : dx0;
                    const float adxp = px ? adx1 : adx0;
                    const float axp  = px ? ax1 : ax0;
                    float q = dxp * (adxp + bdyp) + cdyp;
                    float bil = -((q + axp) + cyp);
                    bil = fminf(fmaxf(bil, -20.0f), 0.0f);
                    bil = inside ? bil : -1e9f;   // exp flushes to +0
                    float w = op * __expf(bil);
                    if (py == 0 && px == 0) { S00 += w; mn00 = fminf(mn00, w); mx00 = fmaxf(mx00, w); }
                    if (py == 0 && px == 1) { S01 += w; mn01 = fminf(mn01, w); mx01 = fmaxf(mx01, w); }
                    if (py == 1 && px == 0) { S10 += w; mn10 = fminf(mn10, w); mx10 = fmaxf(mx10, w); }
                    if (py == 1 && px == 1) { S11 += w; mn11 = fminf(mn11, w); mx11 = fmaxf(mx11, w); }
                }
            }
        }
    }
    if (wave > 0) {
        pS[wave - 1][lane]  = make_float4(S00, S01, S10, S11);
        pMn[wave - 1][lane] = make_float4(mn00, mn01, mn10, mn11);
        pMx[wave - 1][lane] = make_float4(mx00, mx01, mx10, mx11);
    }
    __syncthreads();
    if (wave == 0) {
        #pragma unroll
        for (int w = 0; w < 7; ++w) {
            float4 s = pS[w][lane], mnw = pMn[w][lane], mxw = pMx[w][lane];
            S00 += s.x; S01 += s.y; S10 += s.z; S11 += s.w;
            mn00 = fminf(mn00, mnw.x); mn01 = fminf(mn01, mnw.y);
            mn10 = fminf(mn10, mnw.z); mn11 = fminf(mn11, mnw.w);
            mx00 = fmaxf(mx00, mxw.x); mx01 = fmaxf(mx01, mxw.y);
            mx10 = fmaxf(mx10, mxw.z); mx11 = fmaxf(mx11, mxw.w);
        }
        if (len < 512) {  // culled gaussians contribute w=0 (also fixes len==0 INFs)
            mn00 = fminf(mn00, 0.f); mn01 = fminf(mn01, 0.f);
            mn10 = fminf(mn10, 0.f); mn11 = fminf(mn11, 0.f);
            mx00 = fmaxf(mx00, 0.f); mx01 = fmaxf(mx01, 0.f);
            mx10 = fmaxf(mx10, 0.f); mx11 = fmaxf(mx11, 0.f);
        }
        float S4[4]  = {S00, S01, S10, S11};
        float mn4[4] = {mn00, mn01, mn10, mn11};
        float mx4[4] = {mx00, mx01, mx10, mx11};
        #pragma unroll
        for (int pp = 0; pp < 4; ++pp) {
            const int py = pp >> 1, px = pp & 1;
            const int y = ty0 + 2 * qy + py, x = tx0 + 2 * qx + px;
            float* pb = part + ((v * 224 + y) * 224 + x) * 12 + kk;
            pb[0] = S4[pp];   // S  partial (slot kk)
            pb[4] = mn4[pp];  // mn partial
            pb[8] = mx4[pp];  // mx partial
        }
    }
}

// Merge K=4 partials per halo pixel -> dmv -> d1 = where(d, blur(d));
// d2 = where(d1, blur(d1)); per-block (sum,sumsq) -> cheap LLC barrier ->
// every block reduces 588 partials (double) and writes out from registers.
__global__ __launch_bounds__(256, 3) void blur_norm_kernel(
    const float* __restrict__ part, float* __restrict__ out,
    float2* __restrict__ partials, unsigned* __restrict__ cnts) {
    __shared__ float A[28 * 29];
    __shared__ float T[28 * 29];
    __shared__ float r1[4], r2[4];
    __shared__ double s1[256], s2[256];
    const int v = blockIdx.z;
    const int tx0 = blockIdx.x * 16, ty0 = blockIdx.y * 16;
    const int tid = threadIdx.x;
    const int lane = tid & 63, wave = tid >> 6;
    const int bid = (v * 14 + blockIdx.y) * 14 + blockIdx.x;
    const float kw[7] = {0.00443305f, 0.05400558f, 0.24203623f, 0.39905030f,
                         0.24203623f, 0.05400558f, 0.00443305f};

    for (int idx = tid; idx < 28 * 28; idx += 256) {
        int rr = idx / 28, c = idx % 28;
        int gyy = ty0 - 6 + rr, gxx = tx0 - 6 + c;
        float val = 0.0f;
        if (gyy >= 0 && gyy < 224 && gxx >= 0 && gxx < 224) {
            const float* pb = part + ((v * 224 + gyy) * 224 + gxx) * 12;
            const float4 Sv  = *(const float4*)(pb);
            const float4 mnv = *(const float4*)(pb + 4);
            const float4 mxv = *(const float4*)(pb + 8);
            float S  = (Sv.x + Sv.y) + (Sv.z + Sv.w);
            float mn = fminf(fminf(mnv.x, mnv.y), fminf(mnv.z, mnv.w));
            float mx = fmaxf(fmaxf(mxv.x, mxv.y), fmaxf(mxv.z, mxv.w));
            val = 0.5f * (S - 512.0f * mn) / (mx - mn + 1e-6f) + S / (S + 1e-6f);
        }
        A[rr * 29 + c] = val;
    }
    __syncthreads();
    for (int idx = tid; idx < 22 * 28; idx += 256) {
        int rr = 3 + idx / 28, c = idx % 28;
        float s = 0.0f;
        #pragma unroll
        for (int i = 0; i < 7; ++i) s += kw[i] * A[(rr - 3 + i) * 29 + c];
        T[rr * 29 + c] = s;
    }
    __syncthreads();
    for (int idx = tid; idx < 22 * 22; idx += 256) {
        int rr = 3 + idx / 22, c = 3 + idx % 22;
        int gyy = ty0 - 6 + rr, gxx = tx0 - 6 + c;
        float s = 0.0f;
        #pragma unroll
        for (int j = 0; j < 7; ++j) s += kw[j] * T[rr * 29 + c - 3 + j];
        float ctr = A[rr * 29 + c];
        float d1 = ctr > 1e-6f ? ctr : s;
        if (gyy < 0 || gyy > 223 || gxx < 0 || gxx > 223) d1 = 0.0f;
        A[rr * 29 + c] = d1;
    }
    __syncthreads();
    for (int idx = tid; idx < 16 * 22; idx += 256) {
        int rr = 6 + idx / 22, c = 3 + idx % 22;
        float s = 0.0f;
        #pragma unroll
        for (int i = 0; i < 7; ++i) s += kw[i] * A[(rr - 3 + i) * 29 + c];
        T[rr * 29 + c] = s;
    }
    __syncthreads();
    // one output px per thread; KEEP d2 in a register across the barrier
    const int rr2 = 6 + (tid >> 4), cc2 = 6 + (tid & 15);
    float d2;
    {
        float s = 0.0f;
        #pragma unroll
        for (int j = 0; j < 7; ++j) s += kw[j] * T[rr2 * 29 + cc2 - 3 + j];
        float ctr = A[rr2 * 29 + cc2];
        d2 = ctr > 1e-6f ? ctr : s;
    }
    float ls1 = d2, ls2 = d2 * d2;
    #pragma unroll
    for (int o = 32; o >= 1; o >>= 1) {
        ls1 += __shfl_xor(ls1, o);
        ls2 += __shfl_xor(ls2, o);
    }
    if (lane == 0) { r1[wave] = ls1; r2[wave] = ls2; }
    __syncthreads();
    if (tid == 0) {
        float a = r1[0] + r1[1] + r1[2] + r1[3];
        float b = r2[0] + r2[1] + r2[2] + r2[3];
        float* pb = (float*)&partials[bid];
        g_st(pb + 0, a);
        g_st(pb + 1, b);
    }

    grid_barrier(cnts, bid & (NARR - 1), bid == 0);  // partials visible at LLC

    // global stats from 588 partials (double), then normalize from registers
    double a = 0.0, b = 0.0;
    const float* pb = (const float*)partials;
    for (int i = tid; i < 588; i += 256) {
        a += (double)g_ld(pb + 2 * i);
        b += (double)g_ld(pb + 2 * i + 1);
    }
    s1[tid] = a; s2[tid] = b;
    __syncthreads();
    for (int s = 128; s >= 1; s >>= 1) {
        if (tid < s) { s1[tid] += s1[tid + s]; s2[tid] += s2[tid + s]; }
        __syncthreads();
    }
    const double M = 150528.0;
    double mean = s1[0] / M;
    double var = (s2[0] - M * mean * mean) / (M - 1.0);
    double sd = sqrt(var > 0.0 ? var : 0.0);
    const float fmean = (float)mean;
    const float finv = 1.0f / ((float)sd + 1e-6f);
    out[(v * 224 + ty0 + (tid >> 4)) * 224 + tx0 + (tid & 15)] =
        (d2 - fmean) * finv;
}

extern "C" void kernel_launch(void* const* d_in, const int* in_sizes, int n_in,
                              void* d_out, int out_size, void* d_ws, size_t ws_size,
                              hipStream_t stream) {
    const float* position   = (const float*)d_in[0];  // (1,512,3)
    const float* cov3d      = (const float*)d_in[1];  // (1,512,3,3)
    const float* opacity    = (const float*)d_in[2];  // (1,512)
    const float* importance = (const float*)d_in[3];  // (1,1000)
    float* out = (float*)d_out;                       // (1,3,224,224)

    float* part      = (float*)d_ws;                            // 3*224*224*12 floats
    float2* partials = (float2*)((float*)d_ws + 1806336);       // 588 float2
    unsigned* cnts   = (unsigned*)((float*)d_ws + 1806336 + 1176);  // 1025 u32

    hipLaunchKernelGGL(splat_part_kernel, dim3(14, 14, 3 * KSPLIT), dim3(512), 0,
                       stream, position, cov3d, opacity, importance, part, cnts);
    hipLaunchKernelGGL(blur_norm_kernel, dim3(14, 14, 3), dim3(256), 0, stream,
                       part, out, partials, cnts);
}

// Round 6
// 97.023 us; speedup vs baseline: 1.1211x; 1.1211x over previous
//
#include <hip/hip_runtime.h>
#include <math.h>

// ---------------------------------------------------------------------------
// FullGaussianProjector: B=1, N=512, 3 views, 224x224 out, half-res 112x112.
// R11: KSPLIT=4 hot-tile split, with R10's two regressions removed. 3 dispatches:
//   k0 setup (grid 3, 512 thr): per-view per-gaussian {Aa,2Ab,Ac,opimp,gx,gy}
//     computed ONCE (R10 recomputed it in all 2352 splat blocks). Also does
//     the position min/max reduce (fmin/fmax exact in any order) and clears
//     the barrier counters.
//   k1 splat (grid 14x14x12, 512 thr): z = v*4+kk. Light prologue: 2 coalesced
//     loads/gaussian + cull + DETERMINISTIC scan compact (all kk sub-blocks
//     build the identical list). Evaluate chunk kk (chunks ((kk<<3)+wave),
//     same partition as R10 which passed). Write per-quad float4 partials
//     (S4, mn4, mx4) to SoA planes plane[(kk*3+v)][yh*112+xh] -> 16B/lane
//     CONTIGUOUS stores (R10 used stride-48B scalar stores = ~24 lines/inst).
//   k2 blur_norm (grid 14x14x3, 256 thr): merge 4 kk partials per halo px
//     (12 stride-4 dword loads), closed-form dmv, then R9-proven blur2 +
//     stats + cheap LLC grid barrier (spread arrival, single poller,
//     read-only release) + normalize from registers; out written once.
// Closed forms:
//   dmv = 0.5*(S - 512*mn)/(mx - mn + eps) + S/(S + eps)
//   bilinear(quadratic) = quad(Ex,Ey) - (a*Vx + c*Vy)
// NOTE (R5 lesson): a,2b,c,op must stay f32 — bf16 on the exponent path
// fails absmax through the (wmax-wmin) normalization.
// ---------------------------------------------------------------------------

#define NBLOCKS 588u
#define NARR 32                // arrival counters, one per 128B cacheline
#define FLAG_IDX (NARR * 32)   // release flag, its own cacheline
#define KSPLIT 4
#define QOFF 12544             // 112*112 quads per (kk,v) plane
#define MNOFF 602112           // 12*QOFF*4 floats of S planes
#define MXOFF 1204224

__device__ __forceinline__ float g_ld(const float* p) {
    return __hip_atomic_load(p, __ATOMIC_RELAXED, __HIP_MEMORY_SCOPE_AGENT);
}
__device__ __forceinline__ void g_st(float* p, float v) {
    __hip_atomic_store(p, v, __ATOMIC_RELAXED, __HIP_MEMORY_SCOPE_AGENT);
}

// Cheap grid barrier: spread arrival + single poller + broadcast release.
__device__ __forceinline__ void grid_barrier(unsigned* cnts, int arrIdx, bool poller) {
    __syncthreads();
    if (threadIdx.x == 0) {
        asm volatile("s_waitcnt vmcnt(0)" ::: "memory");  // partials acked at LLC
        __hip_atomic_fetch_add(&cnts[arrIdx * 32], 1u,
                               __ATOMIC_RELAXED, __HIP_MEMORY_SCOPE_AGENT);
        unsigned* flagp = &cnts[FLAG_IDX];
        if (poller) {
            for (;;) {
                unsigned s = 0;
                #pragma unroll
                for (int i = 0; i < NARR; ++i)
                    s += __hip_atomic_load(&cnts[i * 32],
                                           __ATOMIC_RELAXED, __HIP_MEMORY_SCOPE_AGENT);
                if (s == NBLOCKS) break;
                __builtin_amdgcn_s_sleep(2);
            }
            asm volatile("" ::: "memory");  // flag store after poll loads
            __hip_atomic_store(flagp, 1u, __ATOMIC_RELAXED, __HIP_MEMORY_SCOPE_AGENT);
        } else {
            while (__hip_atomic_load(flagp, __ATOMIC_RELAXED,
                                     __HIP_MEMORY_SCOPE_AGENT) == 0u)
                __builtin_amdgcn_s_sleep(2);
        }
    }
    __syncthreads();
}

__device__ __forceinline__ float wave_min(float v) {
    #pragma unroll
    for (int o = 32; o >= 1; o >>= 1) v = fminf(v, __shfl_xor(v, o));
    return v;
}

// ---------------- k0: per-(view,gaussian) setup, computed once ----------------
__global__ __launch_bounds__(512) void setup_kernel(
    const float* __restrict__ position, const float* __restrict__ cov3d,
    const float* __restrict__ opacity, const float* __restrict__ importance,
    float4* __restrict__ abc, float2* __restrict__ gxy,
    unsigned* __restrict__ cnts) {
    __shared__ float red[8 * 6];
    const int v = blockIdx.x;
    const int tid = threadIdx.x;
    const int lane = tid & 63, wave = tid >> 6;

    if (v == 0) {
        for (int i = tid; i <= FLAG_IDX; i += 512) cnts[i] = 0;
    }

    const int n = tid;
    const float p0 = position[n * 3 + 0];
    const float p1 = position[n * 3 + 1];
    const float p2 = position[n * 3 + 2];
    const float opimp = opacity[n] * fminf(fmaxf(importance[n], 0.5f), 2.0f);

    {
        float vals[6] = {p0, -p0, p1, -p1, p2, -p2};
        #pragma unroll
        for (int k = 0; k < 6; ++k) {
            float r = wave_min(vals[k]);
            if (lane == 0) red[wave * 6 + k] = r;
        }
    }
    __syncthreads();
    float mn6[6];
    #pragma unroll
    for (int k = 0; k < 6; ++k) {
        float r = red[k];
        #pragma unroll
        for (int w = 1; w < 8; ++w) r = fminf(r, red[w * 6 + k]);
        mn6[k] = r;
    }
    const float pmn[3] = {mn6[0], mn6[2], mn6[4]};
    const float pmx[3] = {-mn6[1], -mn6[3], -mn6[5]};

    float c00 = cov3d[n * 9 + 0], c01 = cov3d[n * 9 + 1], c02 = cov3d[n * 9 + 2];
    float c10 = cov3d[n * 9 + 3], c11 = cov3d[n * 9 + 4], c12 = cov3d[n * 9 + 5];
    float c20 = cov3d[n * 9 + 6], c21 = cov3d[n * 9 + 7], c22 = cov3d[n * 9 + 8];
    for (int vv = 0; vv <= v; ++vv) {
        float s01 = 0.5f * (c01 + c10);
        float s02 = 0.5f * (c02 + c20);
        float s12 = 0.5f * (c12 + c21);
        float s00 = c00 + 1e-6f;
        float s11 = c11 + 1e-6f;
        float s22 = c22 + 1e-6f;
        float nrm = sqrtf(s00 * s00 + s11 * s11 + s22 * s22 +
                          2.0f * (s01 * s01 + s02 * s02 + s12 * s12));
        float inv = 1.0f / (nrm + 1e-6f);
        c00 = s00 * inv; c11 = s11 * inv; c22 = s22 * inv;
        c01 = s01 * inv; c10 = c01; c02 = s02 * inv; c20 = c02;
        c12 = s12 * inv; c21 = c12;
    }
    float cof00 = c11 * c22 - c12 * c12;
    float cof01 = c02 * c12 - c01 * c22;
    float cof02 = c01 * c12 - c02 * c11;
    float det = c00 * cof00 + c01 * cof01 + c02 * cof02;
    float idet = 1.0f / det;
    float i00 = cof00 * idet;
    float i01 = cof01 * idet;
    float i02 = cof02 * idet;
    float i11 = (c00 * c22 - c02 * c02) * idet;
    float i12 = (c02 * c01 - c00 * c12) * idet;
    float i22 = (c00 * c11 - c01 * c01) * idet;

    float Aa, Ab, Ac, prx, pry;
    int ix, iy;
    if (v == 0)      { Aa = i00; Ab = i01; Ac = i11; prx = p0; pry = p1; ix = 0; iy = 1; }
    else if (v == 1) { Aa = i00; Ab = i02; Ac = i22; prx = p0; pry = p2; ix = 0; iy = 2; }
    else             { Aa = i22; Ab = i12; Ac = i11; prx = p2; pry = p1; ix = 2; iy = 1; }
    Aa += 1e-10f;
    Ac += 1e-10f;

    float mnx = pmn[ix], mxx = pmx[ix], mny = pmn[iy], mxy = pmx[iy];
    float rngx = mxx - mnx + 1e-6f;
    float mnx2 = mnx - 0.5f * rngx;
    float mxx2 = mxx + 0.5f * rngx;
    rngx = mxx2 - mnx2 + 1e-6f;
    float rngy = mxy - mny + 1e-6f;
    float mny2 = mny - 0.5f * rngy;
    float mxy2 = mxy + 0.5f * rngy;
    rngy = mxy2 - mny2 + 1e-6f;
    float gx = fminf(fmaxf((prx - mnx2) / rngx * 111.0f, 0.0f), 111.0f);
    float gy = fminf(fmaxf((pry - mny2) / rngy * 111.0f, 0.0f), 111.0f);

    abc[v * 512 + n] = make_float4(Aa, 2.0f * Ab, Ac, opimp);
    gxy[v * 512 + n] = make_float2(gx, gy);
}

// ---------------- k1: splat partials, z = v*4 + kk ----------------
__global__ __launch_bounds__(512) void splat_part_kernel(
    const float4* __restrict__ abc, const float2* __restrict__ gxy,
    float* __restrict__ part) {
    __shared__ float4 lsA[512];        // a, 2b, c, op
    __shared__ float2 lsB[512];        // gx, gy
    __shared__ int wcnt[8];            // per-wave cull counts (deterministic scan)
    __shared__ float4 pS[7][64], pMn[7][64], pMx[7][64];
    const int v  = blockIdx.z >> 2;
    const int kk = blockIdx.z & 3;
    const int tx0 = blockIdx.x * 16, ty0 = blockIdx.y * 16;
    const int tid = threadIdx.x;
    const int lane = tid & 63, wave = tid >> 6;

    // light prologue: load precomputed per-gaussian params (coalesced)
    const float4 a4 = abc[v * 512 + tid];
    const float2 g2 = gxy[v * 512 + tid];

    // ------- cull + DETERMINISTIC compact into LDS -------
    unsigned long long m;
    bool pass;
    {
        const float bx0 = (float)(tx0 >> 1), bx1 = (float)((tx0 + 15) >> 1);
        const float by0 = (float)(ty0 >> 1), by1 = (float)((ty0 + 15) >> 1);
        float dx = fmaxf(fmaxf(bx0 - g2.x, g2.x - bx1), 0.0f);
        float dy = fmaxf(fmaxf(by0 - g2.y, g2.y - by1), 0.0f);
        pass = (dx * dx + dy * dy) < 400.01f;  // conservative superset
        m = __ballot(pass);
        if (lane == 0) wcnt[wave] = __popcll(m);
    }
    __syncthreads();
    int base = 0, lentot = 0;
    #pragma unroll
    for (int w = 0; w < 8; ++w) {
        int c = wcnt[w];
        if (w < wave) base += c;
        lentot += c;
    }
    if (pass) {
        int slot = base + __popcll(m & ((1ull << lane) - 1ull));
        lsA[slot] = a4;
        lsB[slot] = g2;
    }
    __syncthreads();
    const int len = lentot;

    // quad owned by this lane: half-res pixel (xh, yh)
    const int qx = lane & 7, qy = lane >> 3;
    const int xh = (tx0 >> 1) + qx;
    const int yh = (ty0 >> 1) + qy;

    // npad multiple of 64 so each of the 32 (K*waves) chunks is even-sized
    const int npad = (len + 63) & ~63;
    if (tid < npad - len) {  // no-op pad gaussians (mask always fails -> w=0)
        lsA[len + tid] = make_float4(1.0f, 0.0f, 1.0f, 0.0f);
        lsB[len + tid] = make_float2(1e9f, 1e9f);
    }
    __syncthreads();

    // per-parity constants (generic formula, preserves edge clamping exactly)
    float exA[2], eyA[2], VxA[2], VyA[2];
    #pragma unroll
    for (int p = 0; p < 2; ++p) {
        int xlo = xh - 1 + p; int xhi = min(xlo + 1, 111); xlo = max(xlo, 0);
        float wlo = p ? 0.75f : 0.25f, whi = 1.0f - wlo;
        exA[p] = wlo * (float)xlo + whi * (float)xhi;
        VxA[p] = wlo * whi * (float)(xhi - xlo) * (float)(xhi - xlo);
        int ylo = yh - 1 + p; int yhi2 = min(ylo + 1, 111); ylo = max(ylo, 0);
        eyA[p] = wlo * (float)ylo + whi * (float)yhi2;
        VyA[p] = wlo * whi * (float)(yhi2 - ylo) * (float)(yhi2 - ylo);
    }
    const float fxh = (float)xh, fyh = (float)yh;

    // ------- list chunk for this (sub-block, wave): 1/32 of the list -------
    const int chunk = npad >> 5;           // even (npad multiple of 64)
    const int cbeg = ((kk << 3) + wave) * chunk, cend = cbeg + chunk;

    float S00 = 0.f, S01 = 0.f, S10 = 0.f, S11 = 0.f;
    float mn00 = INFINITY, mn01 = INFINITY, mn10 = INFINITY, mn11 = INFINITY;
    float mx00 = -INFINITY, mx01 = -INFINITY, mx10 = -INFINITY, mx11 = -INFINITY;

    for (int i = cbeg; i < cend; i += 2) {
        float4 gA0 = lsA[i], gA1 = lsA[i + 1];
        float2 gB0 = lsB[i], gB1 = lsB[i + 1];
        #pragma unroll
        for (int u = 0; u < 2; ++u) {
            const float4 gA = u ? gA1 : gA0;
            const float2 gB = u ? gB1 : gB0;
            const float a = gA.x, b2 = gA.y, c = gA.z, op = gA.w;
            const float xx = gB.x, yy = gB.y;
            const float dxh = fxh - xx, dyh = fyh - yy;
            const bool inside = dxh * dxh + dyh * dyh < 400.0f;
            const float dx0 = exA[0] - xx, dx1 = exA[1] - xx;
            const float dy0 = eyA[0] - yy, dy1 = eyA[1] - yy;
            const float adx0 = a * dx0, adx1 = a * dx1;
            const float bdy0 = b2 * dy0, bdy1 = b2 * dy1;
            const float cdy0 = c * dy0 * dy0, cdy1 = c * dy1 * dy1;
            const float ax0 = a * VxA[0], ax1 = a * VxA[1];
            const float cy0 = c * VyA[0], cy1 = c * VyA[1];
            #pragma unroll
            for (int py = 0; py < 2; ++py) {
                const float bdyp = py ? bdy1 : bdy0;
                const float cdyp = py ? cdy1 : cdy0;
                const float cyp  = py ? cy1 : cy0;
                #pragma unroll
                for (int px = 0; px < 2; ++px) {
                    const float dxp  = px ? dx1 : dx0;
                    const float adxp = px ? adx1 : adx0;
                    const float axp  = px ? ax1 : ax0;
                    float q = dxp * (adxp + bdyp) + cdyp;
                    float bil = -((q + axp) + cyp);
                    bil = fminf(fmaxf(bil, -20.0f), 0.0f);
                    bil = inside ? bil : -1e9f;   // exp flushes to +0
                    float w = op * __expf(bil);
                    if (py == 0 && px == 0) { S00 += w; mn00 = fminf(mn00, w); mx00 = fmaxf(mx00, w); }
                    if (py == 0 && px == 1) { S01 += w; mn01 = fminf(mn01, w); mx01 = fmaxf(mx01, w); }
                    if (py == 1 && px == 0) { S10 += w; mn10 = fminf(mn10, w); mx10 = fmaxf(mx10, w); }
                    if (py == 1 && px == 1) { S11 += w; mn11 = fminf(mn11, w); mx11 = fmaxf(mx11, w); }
                }
            }
        }
    }
    if (wave > 0) {
        pS[wave - 1][lane]  = make_float4(S00, S01, S10, S11);
        pMn[wave - 1][lane] = make_float4(mn00, mn01, mn10, mn11);
        pMx[wave - 1][lane] = make_float4(mx00, mx01, mx10, mx11);
    }
    __syncthreads();
    if (wave == 0) {
        #pragma unroll
        for (int w = 0; w < 7; ++w) {
            float4 s = pS[w][lane], mnw = pMn[w][lane], mxw = pMx[w][lane];
            S00 += s.x; S01 += s.y; S10 += s.z; S11 += s.w;
            mn00 = fminf(mn00, mnw.x); mn01 = fminf(mn01, mnw.y);
            mn10 = fminf(mn10, mnw.z); mn11 = fminf(mn11, mnw.w);
            mx00 = fmaxf(mx00, mxw.x); mx01 = fmaxf(mx01, mxw.y);
            mx10 = fmaxf(mx10, mxw.z); mx11 = fmaxf(mx11, mxw.w);
        }
        if (len < 512) {  // culled gaussians contribute w=0 (also fixes len==0 INFs)
            mn00 = fminf(mn00, 0.f); mn01 = fminf(mn01, 0.f);
            mn10 = fminf(mn10, 0.f); mn11 = fminf(mn11, 0.f);
            mx00 = fmaxf(mx00, 0.f); mx01 = fmaxf(mx01, 0.f);
            mx10 = fmaxf(mx10, 0.f); mx11 = fmaxf(mx11, 0.f);
        }
        // coalesced float4 quad stores into SoA planes
        const int qidx = (kk * 3 + v) * QOFF + yh * 112 + xh;
        ((float4*)(part))[qidx]          = make_float4(S00, S01, S10, S11);
        ((float4*)(part + MNOFF))[qidx]  = make_float4(mn00, mn01, mn10, mn11);
        ((float4*)(part + MXOFF))[qidx]  = make_float4(mx00, mx01, mx10, mx11);
    }
}

// ---------------- k2: merge + blur2 + stats + barrier + normalize ----------------
__global__ __launch_bounds__(256, 3) void blur_norm_kernel(
    const float* __restrict__ part, float* __restrict__ out,
    float2* __restrict__ partials, unsigned* __restrict__ cnts) {
    __shared__ float A[28 * 29];
    __shared__ float T[28 * 29];
    __shared__ float r1[4], r2[4];
    __shared__ double s1[256], s2[256];
    const int v = blockIdx.z;
    const int tx0 = blockIdx.x * 16, ty0 = blockIdx.y * 16;
    const int tid = threadIdx.x;
    const int lane = tid & 63, wave = tid >> 6;
    const int bid = (v * 14 + blockIdx.y) * 14 + blockIdx.x;
    const float kw[7] = {0.00443305f, 0.05400558f, 0.24203623f, 0.39905030f,
                         0.24203623f, 0.05400558f, 0.00443305f};

    for (int idx = tid; idx < 28 * 28; idx += 256) {
        int rr = idx / 28, c = idx % 28;
        int gyy = ty0 - 6 + rr, gxx = tx0 - 6 + c;
        float val = 0.0f;
        if (gyy >= 0 && gyy < 224 && gxx >= 0 && gxx < 224) {
            const int qb = (gyy >> 1) * 112 + (gxx >> 1);
            const int comp = ((gyy & 1) << 1) | (gxx & 1);
            float S = 0.0f, mn = INFINITY, mx = -INFINITY;
            #pragma unroll
            for (int k = 0; k < KSPLIT; ++k) {
                const int fi = ((k * 3 + v) * QOFF + qb) * 4 + comp;
                S += part[fi];
                mn = fminf(mn, part[MNOFF + fi]);
                mx = fmaxf(mx, part[MXOFF + fi]);
            }
            val = 0.5f * (S - 512.0f * mn) / (mx - mn + 1e-6f) + S / (S + 1e-6f);
        }
        A[rr * 29 + c] = val;
    }
    __syncthreads();
    for (int idx = tid; idx < 22 * 28; idx += 256) {
        int rr = 3 + idx / 28, c = idx % 28;
        float s = 0.0f;
        #pragma unroll
        for (int i = 0; i < 7; ++i) s += kw[i] * A[(rr - 3 + i) * 29 + c];
        T[rr * 29 + c] = s;
    }
    __syncthreads();
    for (int idx = tid; idx < 22 * 22; idx += 256) {
        int rr = 3 + idx / 22, c = 3 + idx % 22;
        int gyy = ty0 - 6 + rr, gxx = tx0 - 6 + c;
        float s = 0.0f;
        #pragma unroll
        for (int j = 0; j < 7; ++j) s += kw[j] * T[rr * 29 + c - 3 + j];
        float ctr = A[rr * 29 + c];
        float d1 = ctr > 1e-6f ? ctr : s;
        if (gyy < 0 || gyy > 223 || gxx < 0 || gxx > 223) d1 = 0.0f;
        A[rr * 29 + c] = d1;
    }
    __syncthreads();
    for (int idx = tid; idx < 16 * 22; idx += 256) {
        int rr = 6 + idx / 22, c = 3 + idx % 22;
        float s = 0.0f;
        #pragma unroll
        for (int i = 0; i < 7; ++i) s += kw[i] * A[(rr - 3 + i) * 29 + c];
        T[rr * 29 + c] = s;
    }
    __syncthreads();
    // one output px per thread; KEEP d2 in a register across the barrier
    const int rr2 = 6 + (tid >> 4), cc2 = 6 + (tid & 15);
    float d2;
    {
        float s = 0.0f;
        #pragma unroll
        for (int j = 0; j < 7; ++j) s += kw[j] * T[rr2 * 29 + cc2 - 3 + j];
        float ctr = A[rr2 * 29 + cc2];
        d2 = ctr > 1e-6f ? ctr : s;
    }
    float ls1 = d2, ls2 = d2 * d2;
    #pragma unroll
    for (int o = 32; o >= 1; o >>= 1) {
        ls1 += __shfl_xor(ls1, o);
        ls2 += __shfl_xor(ls2, o);
    }
    if (lane == 0) { r1[wave] = ls1; r2[wave] = ls2; }
    __syncthreads();
    if (tid == 0) {
        float a = r1[0] + r1[1] + r1[2] + r1[3];
        float b = r2[0] + r2[1] + r2[2] + r2[3];
        float* pb = (float*)&partials[bid];
        g_st(pb + 0, a);
        g_st(pb + 1, b);
    }

    grid_barrier(cnts, bid & (NARR - 1), bid == 0);  // partials visible at LLC

    // global stats from 588 partials (double), then normalize from registers
    double a = 0.0, b = 0.0;
    const float* pb = (const float*)partials;
    for (int i = tid; i < 588; i += 256) {
        a += (double)g_ld(pb + 2 * i);
        b += (double)g_ld(pb + 2 * i + 1);
    }
    s1[tid] = a; s2[tid] = b;
    __syncthreads();
    for (int s = 128; s >= 1; s >>= 1) {
        if (tid < s) { s1[tid] += s1[tid + s]; s2[tid] += s2[tid + s]; }
        __syncthreads();
    }
    const double M = 150528.0;
    double mean = s1[0] / M;
    double var = (s2[0] - M * mean * mean) / (M - 1.0);
    double sd = sqrt(var > 0.0 ? var : 0.0);
    const float fmean = (float)mean;
    const float finv = 1.0f / ((float)sd + 1e-6f);
    out[(v * 224 + ty0 + (tid >> 4)) * 224 + tx0 + (tid & 15)] =
        (d2 - fmean) * finv;
}

extern "C" void kernel_launch(void* const* d_in, const int* in_sizes, int n_in,
                              void* d_out, int out_size, void* d_ws, size_t ws_size,
                              hipStream_t stream) {
    const float* position   = (const float*)d_in[0];  // (1,512,3)
    const float* cov3d      = (const float*)d_in[1];  // (1,512,3,3)
    const float* opacity    = (const float*)d_in[2];  // (1,512)
    const float* importance = (const float*)d_in[3];  // (1,1000)
    float* out = (float*)d_out;                       // (1,3,224,224)

    float* part      = (float*)d_ws;                            // 1806336 floats
    float2* partials = (float2*)((float*)d_ws + 1806336);       // 588 float2
    unsigned* cnts   = (unsigned*)((float*)d_ws + 1806336 + 1176);  // 1025 u32
    float4* abc      = (float4*)((float*)d_ws + 1808640);       // 3*512 float4
    float2* gxy      = (float2*)((float*)d_ws + 1808640 + 6144);// 3*512 float2

    hipLaunchKernelGGL(setup_kernel, dim3(3), dim3(512), 0, stream,
                       position, cov3d, opacity, importance, abc, gxy, cnts);
    hipLaunchKernelGGL(splat_part_kernel, dim3(14, 14, 3 * KSPLIT), dim3(512), 0,
                       stream, abc, gxy, part);
    hipLaunchKernelGGL(blur_norm_kernel, dim3(14, 14, 3), dim3(256), 0, stream,
                       part, out, partials, cnts);
}

// Round 7
// 93.402 us; speedup vs baseline: 1.1646x; 1.0388x over previous
//
#include <hip/hip_runtime.h>
#include <math.h>

// ---------------------------------------------------------------------------
// FullGaussianProjector: B=1, N=512, 3 views, 224x224 out, half-res 112x112.
// R12: latency-exposure pass on the R11 skeleton. 3 dispatches:
//   k0 setup (grid 3, 512 thr): per-view per-gaussian {Aa,2Ab,Ac,opimp,gx,gy}
//     computed once + position min/max reduce + clears barrier counters.
//   k1 splat (grid 14x14x6, 512 thr): KSPLIT=2 (z = v*2+kk). R11 post-mortem:
//     eval math is ~1-2us device-wide; cost is per-block fixed/latency, so
//     HALVE the block count (2352->1176) and halve the exchange traffic.
//     Deterministic scan compact (all kk sub-blocks build identical lists);
//     chunks ((kk<<3)+wave) of npad (mult 64); per-quad float4 partials to
//     SoA planes plane[(kk*3+v)][yh*112+xh] (coalesced 16B/lane stores).
//   k2 blur_norm (grid 14x14x3, 256 thr): QUAD-grain merge (one thread per
//     half-res quad: 6 float4 loads vs 48 scalar dwords), closed-form dmv,
//     blur2 in LDS, per-block stats -> cheap LLC barrier (spread arrival) ->
//     POLLER-ONLY stats reduce (block 0 computes mean/inv in double, publishes
//     on the flag cacheline; 587 blocks just read 2 floats) -> normalize from
//     registers; out written once.
// Closed forms:
//   dmv = 0.5*(S - 512*mn)/(mx - mn + eps) + S/(S + eps)
//   bilinear(quadratic) = quad(Ex,Ey) - (a*Vx + c*Vy)
// NOTE (R5 lesson): a,2b,c,op must stay f32 — bf16 on the exponent path
// fails absmax through the (wmax-wmin) normalization.
// ---------------------------------------------------------------------------

#define NBLOCKS 588u
#define NARR 32                // arrival counters, one per 128B cacheline
#define FLAG_IDX (NARR * 32)   // release flag, its own cacheline
#define STAT_IDX (FLAG_IDX + 32)  // published (mean, inv) floats
#define KSPLIT 2
#define QOFF 12544             // 112*112 quads per (kk,v) plane
#define MNOFF 301056           // 6*QOFF*4 floats of S planes
#define MXOFF 602112

__device__ __forceinline__ float g_ld(const float* p) {
    return __hip_atomic_load(p, __ATOMIC_RELAXED, __HIP_MEMORY_SCOPE_AGENT);
}
__device__ __forceinline__ void g_st(float* p, float v) {
    __hip_atomic_store(p, v, __ATOMIC_RELAXED, __HIP_MEMORY_SCOPE_AGENT);
}

__device__ __forceinline__ float wave_min(float v) {
    #pragma unroll
    for (int o = 32; o >= 1; o >>= 1) v = fminf(v, __shfl_xor(v, o));
    return v;
}

// ---------------- k0: per-(view,gaussian) setup, computed once ----------------
__global__ __launch_bounds__(512) void setup_kernel(
    const float* __restrict__ position, const float* __restrict__ cov3d,
    const float* __restrict__ opacity, const float* __restrict__ importance,
    float4* __restrict__ abc, float2* __restrict__ gxy,
    unsigned* __restrict__ cnts) {
    __shared__ float red[8 * 6];
    const int v = blockIdx.x;
    const int tid = threadIdx.x;
    const int lane = tid & 63, wave = tid >> 6;

    if (v == 0) {
        for (int i = tid; i < STAT_IDX + 32; i += 512) cnts[i] = 0;
    }

    const int n = tid;
    const float p0 = position[n * 3 + 0];
    const float p1 = position[n * 3 + 1];
    const float p2 = position[n * 3 + 2];
    const float opimp = opacity[n] * fminf(fmaxf(importance[n], 0.5f), 2.0f);

    {
        float vals[6] = {p0, -p0, p1, -p1, p2, -p2};
        #pragma unroll
        for (int k = 0; k < 6; ++k) {
            float r = wave_min(vals[k]);
            if (lane == 0) red[wave * 6 + k] = r;
        }
    }
    __syncthreads();
    float mn6[6];
    #pragma unroll
    for (int k = 0; k < 6; ++k) {
        float r = red[k];
        #pragma unroll
        for (int w = 1; w < 8; ++w) r = fminf(r, red[w * 6 + k]);
        mn6[k] = r;
    }
    const float pmn[3] = {mn6[0], mn6[2], mn6[4]};
    const float pmx[3] = {-mn6[1], -mn6[3], -mn6[5]};

    float c00 = cov3d[n * 9 + 0], c01 = cov3d[n * 9 + 1], c02 = cov3d[n * 9 + 2];
    float c10 = cov3d[n * 9 + 3], c11 = cov3d[n * 9 + 4], c12 = cov3d[n * 9 + 5];
    float c20 = cov3d[n * 9 + 6], c21 = cov3d[n * 9 + 7], c22 = cov3d[n * 9 + 8];
    for (int vv = 0; vv <= v; ++vv) {
        float s01 = 0.5f * (c01 + c10);
        float s02 = 0.5f * (c02 + c20);
        float s12 = 0.5f * (c12 + c21);
        float s00 = c00 + 1e-6f;
        float s11 = c11 + 1e-6f;
        float s22 = c22 + 1e-6f;
        float nrm = sqrtf(s00 * s00 + s11 * s11 + s22 * s22 +
                          2.0f * (s01 * s01 + s02 * s02 + s12 * s12));
        float inv = 1.0f / (nrm + 1e-6f);
        c00 = s00 * inv; c11 = s11 * inv; c22 = s22 * inv;
        c01 = s01 * inv; c10 = c01; c02 = s02 * inv; c20 = c02;
        c12 = s12 * inv; c21 = c12;
    }
    float cof00 = c11 * c22 - c12 * c12;
    float cof01 = c02 * c12 - c01 * c22;
    float cof02 = c01 * c12 - c02 * c11;
    float det = c00 * cof00 + c01 * cof01 + c02 * cof02;
    float idet = 1.0f / det;
    float i00 = cof00 * idet;
    float i01 = cof01 * idet;
    float i02 = cof02 * idet;
    float i11 = (c00 * c22 - c02 * c02) * idet;
    float i12 = (c02 * c01 - c00 * c12) * idet;
    float i22 = (c00 * c11 - c01 * c01) * idet;

    float Aa, Ab, Ac, prx, pry;
    int ix, iy;
    if (v == 0)      { Aa = i00; Ab = i01; Ac = i11; prx = p0; pry = p1; ix = 0; iy = 1; }
    else if (v == 1) { Aa = i00; Ab = i02; Ac = i22; prx = p0; pry = p2; ix = 0; iy = 2; }
    else             { Aa = i22; Ab = i12; Ac = i11; prx = p2; pry = p1; ix = 2; iy = 1; }
    Aa += 1e-10f;
    Ac += 1e-10f;

    float mnx = pmn[ix], mxx = pmx[ix], mny = pmn[iy], mxy = pmx[iy];
    float rngx = mxx - mnx + 1e-6f;
    float mnx2 = mnx - 0.5f * rngx;
    float mxx2 = mxx + 0.5f * rngx;
    rngx = mxx2 - mnx2 + 1e-6f;
    float rngy = mxy - mny + 1e-6f;
    float mny2 = mny - 0.5f * rngy;
    float mxy2 = mxy + 0.5f * rngy;
    rngy = mxy2 - mny2 + 1e-6f;
    float gx = fminf(fmaxf((prx - mnx2) / rngx * 111.0f, 0.0f), 111.0f);
    float gy = fminf(fmaxf((pry - mny2) / rngy * 111.0f, 0.0f), 111.0f);

    abc[v * 512 + n] = make_float4(Aa, 2.0f * Ab, Ac, opimp);
    gxy[v * 512 + n] = make_float2(gx, gy);
}

// ---------------- k1: splat partials, z = v*2 + kk ----------------
__global__ __launch_bounds__(512) void splat_part_kernel(
    const float4* __restrict__ abc, const float2* __restrict__ gxy,
    float* __restrict__ part) {
    __shared__ float4 lsA[512];        // a, 2b, c, op
    __shared__ float2 lsB[512];        // gx, gy
    __shared__ int wcnt[8];            // per-wave cull counts (deterministic scan)
    __shared__ float4 pS[7][64], pMn[7][64], pMx[7][64];
    const int v  = blockIdx.z >> 1;
    const int kk = blockIdx.z & 1;
    const int tx0 = blockIdx.x * 16, ty0 = blockIdx.y * 16;
    const int tid = threadIdx.x;
    const int lane = tid & 63, wave = tid >> 6;

    // light prologue: load precomputed per-gaussian params (coalesced)
    const float4 a4 = abc[v * 512 + tid];
    const float2 g2 = gxy[v * 512 + tid];

    // ------- cull + DETERMINISTIC compact into LDS -------
    unsigned long long m;
    bool pass;
    {
        const float bx0 = (float)(tx0 >> 1), bx1 = (float)((tx0 + 15) >> 1);
        const float by0 = (float)(ty0 >> 1), by1 = (float)((ty0 + 15) >> 1);
        float dx = fmaxf(fmaxf(bx0 - g2.x, g2.x - bx1), 0.0f);
        float dy = fmaxf(fmaxf(by0 - g2.y, g2.y - by1), 0.0f);
        pass = (dx * dx + dy * dy) < 400.01f;  // conservative superset
        m = __ballot(pass);
        if (lane == 0) wcnt[wave] = __popcll(m);
    }
    __syncthreads();
    int base = 0, lentot = 0;
    #pragma unroll
    for (int w = 0; w < 8; ++w) {
        int c = wcnt[w];
        if (w < wave) base += c;
        lentot += c;
    }
    if (pass) {
        int slot = base + __popcll(m & ((1ull << lane) - 1ull));
        lsA[slot] = a4;
        lsB[slot] = g2;
    }
    __syncthreads();
    const int len = lentot;

    // quad owned by this lane: half-res pixel (xh, yh)
    const int qx = lane & 7, qy = lane >> 3;
    const int xh = (tx0 >> 1) + qx;
    const int yh = (ty0 >> 1) + qy;

    // npad multiple of 64 so each of the 16 (K*waves) chunks is even-sized
    const int npad = (len + 63) & ~63;
    if (tid < npad - len) {  // no-op pad gaussians (mask always fails -> w=0)
        lsA[len + tid] = make_float4(1.0f, 0.0f, 1.0f, 0.0f);
        lsB[len + tid] = make_float2(1e9f, 1e9f);
    }
    __syncthreads();

    // per-parity constants (generic formula, preserves edge clamping exactly)
    float exA[2], eyA[2], VxA[2], VyA[2];
    #pragma unroll
    for (int p = 0; p < 2; ++p) {
        int xlo = xh - 1 + p; int xhi = min(xlo + 1, 111); xlo = max(xlo, 0);
        float wlo = p ? 0.75f : 0.25f, whi = 1.0f - wlo;
        exA[p] = wlo * (float)xlo + whi * (float)xhi;
        VxA[p] = wlo * whi * (float)(xhi - xlo) * (float)(xhi - xlo);
        int ylo = yh - 1 + p; int yhi2 = min(ylo + 1, 111); ylo = max(ylo, 0);
        eyA[p] = wlo * (float)ylo + whi * (float)yhi2;
        VyA[p] = wlo * whi * (float)(yhi2 - ylo) * (float)(yhi2 - ylo);
    }
    const float fxh = (float)xh, fyh = (float)yh;

    // ------- list chunk for this (sub-block, wave): 1/16 of the list -------
    const int chunk = npad >> 4;           // multiple of 4
    const int cbeg = ((kk << 3) + wave) * chunk, cend = cbeg + chunk;

    float S00 = 0.f, S01 = 0.f, S10 = 0.f, S11 = 0.f;
    float mn00 = INFINITY, mn01 = INFINITY, mn10 = INFINITY, mn11 = INFINITY;
    float mx00 = -INFINITY, mx01 = -INFINITY, mx10 = -INFINITY, mx11 = -INFINITY;

    for (int i = cbeg; i < cend; i += 2) {
        float4 gA0 = lsA[i], gA1 = lsA[i + 1];
        float2 gB0 = lsB[i], gB1 = lsB[i + 1];
        #pragma unroll
        for (int u = 0; u < 2; ++u) {
            const float4 gA = u ? gA1 : gA0;
            const float2 gB = u ? gB1 : gB0;
            const float a = gA.x, b2 = gA.y, c = gA.z, op = gA.w;
            const float xx = gB.x, yy = gB.y;
            const float dxh = fxh - xx, dyh = fyh - yy;
            const bool inside = dxh * dxh + dyh * dyh < 400.0f;
            const float dx0 = exA[0] - xx, dx1 = exA[1] - xx;
            const float dy0 = eyA[0] - yy, dy1 = eyA[1] - yy;
            const float adx0 = a * dx0, adx1 = a * dx1;
            const float bdy0 = b2 * dy0, bdy1 = b2 * dy1;
            const float cdy0 = c * dy0 * dy0, cdy1 = c * dy1 * dy1;
            const float ax0 = a * VxA[0], ax1 = a * VxA[1];
            const float cy0 = c * VyA[0], cy1 = c * VyA[1];
            #pragma unroll
            for (int py = 0; py < 2; ++py) {
                const float bdyp = py ? bdy1 : bdy0;
                const float cdyp = py ? cdy1 : cdy0;
                const float cyp  = py ? cy1 : cy0;
                #pragma unroll
                for (int px = 0; px < 2; ++px) {
                    const float dxp  = px ? dx1 : dx0;
                    const float adxp = px ? adx1 : adx0;
                    const float axp  = px ? ax1 : ax0;
                    float q = dxp * (adxp + bdyp) + cdyp;
                    float bil = -((q + axp) + cyp);
                    bil = fminf(fmaxf(bil, -20.0f), 0.0f);
                    bil = inside ? bil : -1e9f;   // exp flushes to +0
                    float w = op * __expf(bil);
                    if (py == 0 && px == 0) { S00 += w; mn00 = fminf(mn00, w); mx00 = fmaxf(mx00, w); }
                    if (py == 0 && px == 1) { S01 += w; mn01 = fminf(mn01, w); mx01 = fmaxf(mx01, w); }
                    if (py == 1 && px == 0) { S10 += w; mn10 = fminf(mn10, w); mx10 = fmaxf(mx10, w); }
                    if (py == 1 && px == 1) { S11 += w; mn11 = fminf(mn11, w); mx11 = fmaxf(mx11, w); }
                }
            }
        }
    }
    if (wave > 0) {
        pS[wave - 1][lane]  = make_float4(S00, S01, S10, S11);
        pMn[wave - 1][lane] = make_float4(mn00, mn01, mn10, mn11);
        pMx[wave - 1][lane] = make_float4(mx00, mx01, mx10, mx11);
    }
    __syncthreads();
    if (wave == 0) {
        #pragma unroll
        for (int w = 0; w < 7; ++w) {
            float4 s = pS[w][lane], mnw = pMn[w][lane], mxw = pMx[w][lane];
            S00 += s.x; S01 += s.y; S10 += s.z; S11 += s.w;
            mn00 = fminf(mn00, mnw.x); mn01 = fminf(mn01, mnw.y);
            mn10 = fminf(mn10, mnw.z); mn11 = fminf(mn11, mnw.w);
            mx00 = fmaxf(mx00, mxw.x); mx01 = fmaxf(mx01, mxw.y);
            mx10 = fmaxf(mx10, mxw.z); mx11 = fmaxf(mx11, mxw.w);
        }
        if (len < 512) {  // culled gaussians contribute w=0 (also fixes len==0 INFs)
            mn00 = fminf(mn00, 0.f); mn01 = fminf(mn01, 0.f);
            mn10 = fminf(mn10, 0.f); mn11 = fminf(mn11, 0.f);
            mx00 = fmaxf(mx00, 0.f); mx01 = fmaxf(mx01, 0.f);
            mx10 = fmaxf(mx10, 0.f); mx11 = fmaxf(mx11, 0.f);
        }
        // coalesced float4 quad stores into SoA planes
        const int qidx = (kk * 3 + v) * QOFF + yh * 112 + xh;
        ((float4*)(part))[qidx]          = make_float4(S00, S01, S10, S11);
        ((float4*)(part + MNOFF))[qidx]  = make_float4(mn00, mn01, mn10, mn11);
        ((float4*)(part + MXOFF))[qidx]  = make_float4(mx00, mx01, mx10, mx11);
    }
}

// ---------------- k2: merge + blur2 + stats + barrier + normalize ----------------
__global__ __launch_bounds__(256, 3) void blur_norm_kernel(
    const float* __restrict__ part, float* __restrict__ out,
    float2* __restrict__ partials, unsigned* __restrict__ cnts) {
    __shared__ float A[28 * 29];
    __shared__ float T[28 * 29];
    __shared__ float r1[4], r2[4];
    __shared__ double s1[256], s2[256];
    __shared__ float statLds[2];
    const int v = blockIdx.z;
    const int tx0 = blockIdx.x * 16, ty0 = blockIdx.y * 16;
    const int tid = threadIdx.x;
    const int lane = tid & 63, wave = tid >> 6;
    const int bid = (v * 14 + blockIdx.y) * 14 + blockIdx.x;
    const float kw[7] = {0.00443305f, 0.05400558f, 0.24203623f, 0.39905030f,
                         0.24203623f, 0.05400558f, 0.00443305f};

    // ---- quad-grain merge: one thread per half-res quad (14x14 quads) ----
    // halo px (rr,c) = quad (rr>>1, c>>1), comp ((rr&1)<<1)|(c&1) = py*2+px
    {
        const float4* Sp  = (const float4*)part;
        const float4* Mnp = (const float4*)(part + MNOFF);
        const float4* Mxp = (const float4*)(part + MXOFF);
        const int qy0 = (ty0 - 6) >> 1, qx0 = (tx0 - 6) >> 1;  // even offsets, exact
        if (tid < 196) {
            const int qr = tid / 14, qc = tid % 14;
            const int qgy = qy0 + qr, qgx = qx0 + qc;
            float dmv[4] = {0.0f, 0.0f, 0.0f, 0.0f};
            if (qgy >= 0 && qgy < 112 && qgx >= 0 && qgx < 112) {
                const int qb = qgy * 112 + qgx;
                const float4 S0 = Sp[(0 * 3 + v) * QOFF + qb];
                const float4 S1 = Sp[(1 * 3 + v) * QOFF + qb];
                const float4 n0 = Mnp[(0 * 3 + v) * QOFF + qb];
                const float4 n1 = Mnp[(1 * 3 + v) * QOFF + qb];
                const float4 x0 = Mxp[(0 * 3 + v) * QOFF + qb];
                const float4 x1 = Mxp[(1 * 3 + v) * QOFF + qb];
                const float Sc[4]  = {S0.x + S1.x, S0.y + S1.y, S0.z + S1.z, S0.w + S1.w};
                const float mnc[4] = {fminf(n0.x, n1.x), fminf(n0.y, n1.y),
                                      fminf(n0.z, n1.z), fminf(n0.w, n1.w)};
                const float mxc[4] = {fmaxf(x0.x, x1.x), fmaxf(x0.y, x1.y),
                                      fmaxf(x0.z, x1.z), fmaxf(x0.w, x1.w)};
                #pragma unroll
                for (int cc = 0; cc < 4; ++cc)
                    dmv[cc] = 0.5f * (Sc[cc] - 512.0f * mnc[cc]) / (mxc[cc] - mnc[cc] + 1e-6f)
                            + Sc[cc] / (Sc[cc] + 1e-6f);
            }
            #pragma unroll
            for (int cc = 0; cc < 4; ++cc)
                A[(2 * qr + (cc >> 1)) * 29 + 2 * qc + (cc & 1)] = dmv[cc];
        }
    }
    __syncthreads();
    for (int idx = tid; idx < 22 * 28; idx += 256) {
        int rr = 3 + idx / 28, c = idx % 28;
        float s = 0.0f;
        #pragma unroll
        for (int i = 0; i < 7; ++i) s += kw[i] * A[(rr - 3 + i) * 29 + c];
        T[rr * 29 + c] = s;
    }
    __syncthreads();
    for (int idx = tid; idx < 22 * 22; idx += 256) {
        int rr = 3 + idx / 22, c = 3 + idx % 22;
        int gyy = ty0 - 6 + rr, gxx = tx0 - 6 + c;
        float s = 0.0f;
        #pragma unroll
        for (int j = 0; j < 7; ++j) s += kw[j] * T[rr * 29 + c - 3 + j];
        float ctr = A[rr * 29 + c];
        float d1 = ctr > 1e-6f ? ctr : s;
        if (gyy < 0 || gyy > 223 || gxx < 0 || gxx > 223) d1 = 0.0f;
        A[rr * 29 + c] = d1;
    }
    __syncthreads();
    for (int idx = tid; idx < 16 * 22; idx += 256) {
        int rr = 6 + idx / 22, c = 3 + idx % 22;
        float s = 0.0f;
        #pragma unroll
        for (int i = 0; i < 7; ++i) s += kw[i] * A[(rr - 3 + i) * 29 + c];
        T[rr * 29 + c] = s;
    }
    __syncthreads();
    // one output px per thread; KEEP d2 in a register across the barrier
    const int rr2 = 6 + (tid >> 4), cc2 = 6 + (tid & 15);
    float d2;
    {
        float s = 0.0f;
        #pragma unroll
        for (int j = 0; j < 7; ++j) s += kw[j] * T[rr2 * 29 + cc2 - 3 + j];
        float ctr = A[rr2 * 29 + cc2];
        d2 = ctr > 1e-6f ? ctr : s;
    }
    float ls1 = d2, ls2 = d2 * d2;
    #pragma unroll
    for (int o = 32; o >= 1; o >>= 1) {
        ls1 += __shfl_xor(ls1, o);
        ls2 += __shfl_xor(ls2, o);
    }
    if (lane == 0) { r1[wave] = ls1; r2[wave] = ls2; }
    __syncthreads();

    // ---- arrival: store partial, drain, add to spread counter ----
    if (tid == 0) {
        float a = r1[0] + r1[1] + r1[2] + r1[3];
        float b = r2[0] + r2[1] + r2[2] + r2[3];
        float* pb = (float*)&partials[bid];
        g_st(pb + 0, a);
        g_st(pb + 1, b);
        asm volatile("s_waitcnt vmcnt(0)" ::: "memory");  // partial acked at LLC
        __hip_atomic_fetch_add(&cnts[(bid & (NARR - 1)) * 32], 1u,
                               __ATOMIC_RELAXED, __HIP_MEMORY_SCOPE_AGENT);
    }

    float fmean, finv;
    if (bid == 0) {
        // poller: wait for all arrivals, then compute stats once and publish
        if (tid == 0) {
            for (;;) {
                unsigned s = 0;
                #pragma unroll
                for (int i = 0; i < NARR; ++i)
                    s += __hip_atomic_load(&cnts[i * 32],
                                           __ATOMIC_RELAXED, __HIP_MEMORY_SCOPE_AGENT);
                if (s == NBLOCKS) break;
                __builtin_amdgcn_s_sleep(2);
            }
        }
        __syncthreads();  // all partials visible at LLC
        double a = 0.0, b = 0.0;
        const float* pb = (const float*)partials;
        for (int i = tid; i < 588; i += 256) {
            a += (double)g_ld(pb + 2 * i);
            b += (double)g_ld(pb + 2 * i + 1);
        }
        s1[tid] = a; s2[tid] = b;
        __syncthreads();
        for (int s = 128; s >= 1; s >>= 1) {
            if (tid < s) { s1[tid] += s1[tid + s]; s2[tid] += s2[tid + s]; }
            __syncthreads();
        }
        const double M = 150528.0;
        double mean = s1[0] / M;
        double var = (s2[0] - M * mean * mean) / (M - 1.0);
        double sd = sqrt(var > 0.0 ? var : 0.0);
        fmean = (float)mean;
        finv = 1.0f / ((float)sd + 1e-6f);
        if (tid == 0) {
            float* st = (float*)&cnts[STAT_IDX];
            g_st(st + 0, fmean);
            g_st(st + 1, finv);
            asm volatile("s_waitcnt vmcnt(0)" ::: "memory");  // stats before flag
            __hip_atomic_store(&cnts[FLAG_IDX], 1u,
                               __ATOMIC_RELAXED, __HIP_MEMORY_SCOPE_AGENT);
        }
    } else {
        if (tid == 0) {
            while (__hip_atomic_load(&cnts[FLAG_IDX], __ATOMIC_RELAXED,
                                     __HIP_MEMORY_SCOPE_AGENT) == 0u)
                __builtin_amdgcn_s_sleep(2);
            const float* st = (const float*)&cnts[STAT_IDX];
            statLds[0] = g_ld(st + 0);
            statLds[1] = g_ld(st + 1);
        }
        __syncthreads();
        fmean = statLds[0];
        finv = statLds[1];
    }

    out[(v * 224 + ty0 + (tid >> 4)) * 224 + tx0 + (tid & 15)] =
        (d2 - fmean) * finv;
}

extern "C" void kernel_launch(void* const* d_in, const int* in_sizes, int n_in,
                              void* d_out, int out_size, void* d_ws, size_t ws_size,
                              hipStream_t stream) {
    const float* position   = (const float*)d_in[0];  // (1,512,3)
    const float* cov3d      = (const float*)d_in[1];  // (1,512,3,3)
    const float* opacity    = (const float*)d_in[2];  // (1,512)
    const float* importance = (const float*)d_in[3];  // (1,1000)
    float* out = (float*)d_out;                       // (1,3,224,224)

    float* part      = (float*)d_ws;                            // 903168 floats
    float2* partials = (float2*)((float*)d_ws + 903168);        // 588 float2
    unsigned* cnts   = (unsigned*)((float*)d_ws + 903168 + 1176);  // 1088+ u32
    float4* abc      = (float4*)((float*)d_ws + 905440);        // 3*512 float4
    float2* gxy      = (float2*)((float*)d_ws + 905440 + 6144); // 3*512 float2

    hipLaunchKernelGGL(setup_kernel, dim3(3), dim3(512), 0, stream,
                       position, cov3d, opacity, importance, abc, gxy, cnts);
    hipLaunchKernelGGL(splat_part_kernel, dim3(14, 14, 3 * KSPLIT), dim3(512), 0,
                       stream, abc, gxy, part);
    hipLaunchKernelGGL(blur_norm_kernel, dim3(14, 14, 3), dim3(256), 0, stream,
                       part, out, partials, cnts);
}